// Round 1
// baseline (1730.881 us; speedup 1.0000x reference)
//
#include <hip/hip_runtime.h>
#include <math.h>

// ---------------------------------------------------------------------------
// TransformerBlockQuantum — fp32 baseline (correctness-first, round 1)
//   x:[4,2048,768]  heads=12, dk=64, q=k=v=x
//   attn = softmax(x_h x_h^T / 8) x_h            (flash, never materialize SxS)
//   y1 = attn @ cw^T + x ; h = LN1(y1)
//   meas = cos(h[:,:8]) * cos(theta)
//   y2 = relu(meas @ w1^T) @ w2^T + h ; out = LN2(y2)
// All matmuls fp32 vector-ALU (no fp32 MFMA on CDNA4). bf16-MFMA next round
// once tolerance is known.
// ---------------------------------------------------------------------------

#define B_    4
#define S_    2048
#define D_    768
#define H_    12
#define DK_   64
#define FFN_  3072
#define NQ_   8
#define M_    (B_ * S_)          // 8192 rows

// XOR swizzle of 16B blocks within a 64-float row: conflict-free ds_read_b128
// for both row-gather (A/Q) and col-gather (B/K) access patterns.
#define SWZ(r) ((((r) >> 3) ^ (r)) & 7)

// ---------------------------------------------------------------------------
// Flash attention, fp32. grid (S/128, H, B), block 256.
// Q-tile 128x64 (regs per thread: 8 rows), K/V-tile 64x64 (K tile IS V tile).
// ---------------------------------------------------------------------------
__global__ __launch_bounds__(256, 2)
void attn_kernel(const float* __restrict__ x, float* __restrict__ attn)
{
    __shared__ float Qs[128 * 64];
    __shared__ float Ks[64 * 64];
    __shared__ float Ps[128 * 64];

    const int tid = threadIdx.x;
    const int q0  = blockIdx.x * 128;
    const int hh  = blockIdx.y;
    const int bb  = blockIdx.z;
    const int rg  = tid >> 4;          // 0..15
    const int cg  = tid & 15;          // 0..15
    const int r0  = rg * 8;            // 8 q-rows per thread
    const int c0  = cg * 4;            // 4 cols per thread

    const float* xb = x + (size_t)bb * S_ * D_ + hh * DK_;

    // ---- load Q tile (128 rows x 64), swizzled ----
    #pragma unroll
    for (int it = 0; it < 8; ++it) {
        int idx = tid + it * 256;          // 0..2047
        int r   = idx >> 4;                // 0..127
        int cb  = idx & 15;                // 16B block
        float4 v = *reinterpret_cast<const float4*>(xb + (size_t)(q0 + r) * D_ + cb * 4);
        *reinterpret_cast<float4*>(&Qs[r * 64 + ((cb ^ SWZ(r)) << 2)]) = v;
    }

    float m_run[8], l_run[8], o[8][4];
    #pragma unroll
    for (int i = 0; i < 8; ++i) {
        m_run[i] = -3.0e38f; l_run[i] = 0.f;
        #pragma unroll
        for (int j = 0; j < 4; ++j) o[i][j] = 0.f;
    }

    for (int kt = 0; kt < S_ / 64; ++kt) {
        __syncthreads();                   // prev PV reads of Ks/Ps done
        // ---- load K (=V) tile (64 x 64), swizzled ----
        #pragma unroll
        for (int it = 0; it < 4; ++it) {
            int idx = tid + it * 256;      // 0..1023
            int r   = idx >> 4;            // 0..63
            int cb  = idx & 15;
            float4 v = *reinterpret_cast<const float4*>(xb + (size_t)(kt * 64 + r) * D_ + cb * 4);
            *reinterpret_cast<float4*>(&Ks[r * 64 + ((cb ^ SWZ(r)) << 2)]) = v;
        }
        __syncthreads();

        // ---- S = Q K^T (8x4 per thread) ----
        float s[8][4];
        #pragma unroll
        for (int i = 0; i < 8; ++i)
            #pragma unroll
            for (int j = 0; j < 4; ++j) s[i][j] = 0.f;

        for (int cb = 0; cb < 16; ++cb) {
            float4 a4[8], b4[4];
            #pragma unroll
            for (int i = 0; i < 8; ++i) {
                int r = r0 + i;
                a4[i] = *reinterpret_cast<const float4*>(&Qs[r * 64 + ((cb ^ SWZ(r)) << 2)]);
            }
            #pragma unroll
            for (int j = 0; j < 4; ++j) {
                int c = c0 + j;
                b4[j] = *reinterpret_cast<const float4*>(&Ks[c * 64 + ((cb ^ SWZ(c)) << 2)]);
            }
            #pragma unroll
            for (int i = 0; i < 8; ++i)
                #pragma unroll
                for (int j = 0; j < 4; ++j) {
                    s[i][j] = fmaf(a4[i].x, b4[j].x, s[i][j]);
                    s[i][j] = fmaf(a4[i].y, b4[j].y, s[i][j]);
                    s[i][j] = fmaf(a4[i].z, b4[j].z, s[i][j]);
                    s[i][j] = fmaf(a4[i].w, b4[j].w, s[i][j]);
                }
        }

        // ---- online softmax (row state across the 16 cg-lanes per row) ----
        #pragma unroll
        for (int i = 0; i < 8; ++i) {
            float s0 = s[i][0] * 0.125f, s1 = s[i][1] * 0.125f;
            float s2 = s[i][2] * 0.125f, s3 = s[i][3] * 0.125f;
            float mx = fmaxf(fmaxf(s0, s1), fmaxf(s2, s3));
            #pragma unroll
            for (int msk = 1; msk < 16; msk <<= 1) mx = fmaxf(mx, __shfl_xor(mx, msk));
            float mnew = fmaxf(m_run[i], mx);
            float corr = __expf(m_run[i] - mnew);
            float p0 = __expf(s0 - mnew), p1 = __expf(s1 - mnew);
            float p2 = __expf(s2 - mnew), p3 = __expf(s3 - mnew);
            float ps = (p0 + p1) + (p2 + p3);
            #pragma unroll
            for (int msk = 1; msk < 16; msk <<= 1) ps += __shfl_xor(ps, msk);
            l_run[i] = l_run[i] * corr + ps;
            m_run[i] = mnew;
            #pragma unroll
            for (int j = 0; j < 4; ++j) o[i][j] *= corr;
            int r = r0 + i;
            float4 pv = make_float4(p0, p1, p2, p3);
            *reinterpret_cast<float4*>(&Ps[r * 64 + ((cg ^ SWZ(r)) << 2)]) = pv;
        }
        __syncthreads();                   // Ps visible to all

        // ---- O += P V  (V rows are Ks rows) ----
        for (int cb = 0; cb < 16; ++cb) {
            float4 p4[8], v4[4];
            #pragma unroll
            for (int i = 0; i < 8; ++i) {
                int r = r0 + i;
                p4[i] = *reinterpret_cast<const float4*>(&Ps[r * 64 + ((cb ^ SWZ(r)) << 2)]);
            }
            #pragma unroll
            for (int jc = 0; jc < 4; ++jc) {
                int c = cb * 4 + jc;
                v4[jc] = *reinterpret_cast<const float4*>(&Ks[c * 64 + ((cg ^ SWZ(c)) << 2)]);
            }
            #pragma unroll
            for (int i = 0; i < 8; ++i) {
                o[i][0] = fmaf(p4[i].x, v4[0].x, o[i][0]);
                o[i][1] = fmaf(p4[i].x, v4[0].y, o[i][1]);
                o[i][2] = fmaf(p4[i].x, v4[0].z, o[i][2]);
                o[i][3] = fmaf(p4[i].x, v4[0].w, o[i][3]);
                o[i][0] = fmaf(p4[i].y, v4[1].x, o[i][0]);
                o[i][1] = fmaf(p4[i].y, v4[1].y, o[i][1]);
                o[i][2] = fmaf(p4[i].y, v4[1].z, o[i][2]);
                o[i][3] = fmaf(p4[i].y, v4[1].w, o[i][3]);
                o[i][0] = fmaf(p4[i].z, v4[2].x, o[i][0]);
                o[i][1] = fmaf(p4[i].z, v4[2].y, o[i][1]);
                o[i][2] = fmaf(p4[i].z, v4[2].z, o[i][2]);
                o[i][3] = fmaf(p4[i].z, v4[2].w, o[i][3]);
                o[i][0] = fmaf(p4[i].w, v4[3].x, o[i][0]);
                o[i][1] = fmaf(p4[i].w, v4[3].y, o[i][1]);
                o[i][2] = fmaf(p4[i].w, v4[3].z, o[i][2]);
                o[i][3] = fmaf(p4[i].w, v4[3].w, o[i][3]);
            }
        }
    }

    // ---- epilogue: normalize, write attn[b, q, h*64 + d] ----
    float* ap = attn + (size_t)bb * S_ * D_ + hh * DK_;
    #pragma unroll
    for (int i = 0; i < 8; ++i) {
        float inv = 1.0f / l_run[i];
        float4 vout = make_float4(o[i][0] * inv, o[i][1] * inv, o[i][2] * inv, o[i][3] * inv);
        *reinterpret_cast<float4*>(ap + (size_t)(q0 + r0 + i) * D_ + c0) = vout;
    }
}

// ---------------------------------------------------------------------------
// y1 = attn @ cw^T + x.  grid (M/128, 768/128), block 256, 8x8 per thread.
// ---------------------------------------------------------------------------
__global__ __launch_bounds__(256, 2)
void gemm_combine(const float* __restrict__ A, const float* __restrict__ W,
                  const float* __restrict__ xres, float* __restrict__ y1)
{
    __shared__ float As[128 * 64];
    __shared__ float Bs[128 * 64];
    const int tid = threadIdx.x;
    const int m0 = blockIdx.x * 128, n0 = blockIdx.y * 128;
    const int rg = tid >> 4, cg = tid & 15;
    const int r0 = rg * 8, c0 = cg * 8;

    float acc[8][8];
    #pragma unroll
    for (int i = 0; i < 8; ++i)
        #pragma unroll
        for (int j = 0; j < 8; ++j) acc[i][j] = 0.f;

    for (int k0 = 0; k0 < D_; k0 += 64) {
        __syncthreads();
        #pragma unroll
        for (int it = 0; it < 8; ++it) {
            int idx = tid + it * 256;       // 0..2047
            int r = idx >> 4, cb = idx & 15;
            float4 va = *reinterpret_cast<const float4*>(A + (size_t)(m0 + r) * D_ + k0 + cb * 4);
            *reinterpret_cast<float4*>(&As[r * 64 + ((cb ^ SWZ(r)) << 2)]) = va;
            float4 vb = *reinterpret_cast<const float4*>(W + (size_t)(n0 + r) * D_ + k0 + cb * 4);
            *reinterpret_cast<float4*>(&Bs[r * 64 + ((cb ^ SWZ(r)) << 2)]) = vb;
        }
        __syncthreads();

        for (int cb = 0; cb < 16; ++cb) {
            float4 a4[8], b4[8];
            #pragma unroll
            for (int i = 0; i < 8; ++i) {
                int r = r0 + i;
                a4[i] = *reinterpret_cast<const float4*>(&As[r * 64 + ((cb ^ SWZ(r)) << 2)]);
            }
            #pragma unroll
            for (int j = 0; j < 8; ++j) {
                int c = c0 + j;
                b4[j] = *reinterpret_cast<const float4*>(&Bs[c * 64 + ((cb ^ SWZ(c)) << 2)]);
            }
            #pragma unroll
            for (int i = 0; i < 8; ++i)
                #pragma unroll
                for (int j = 0; j < 8; ++j) {
                    acc[i][j] = fmaf(a4[i].x, b4[j].x, acc[i][j]);
                    acc[i][j] = fmaf(a4[i].y, b4[j].y, acc[i][j]);
                    acc[i][j] = fmaf(a4[i].z, b4[j].z, acc[i][j]);
                    acc[i][j] = fmaf(a4[i].w, b4[j].w, acc[i][j]);
                }
        }
    }

    #pragma unroll
    for (int i = 0; i < 8; ++i) {
        size_t row = (size_t)m0 + r0 + i;
        #pragma unroll
        for (int jb = 0; jb < 2; ++jb) {
            float4 xr = *reinterpret_cast<const float4*>(xres + row * D_ + n0 + c0 + jb * 4);
            float4 ov = make_float4(acc[i][jb*4+0] + xr.x, acc[i][jb*4+1] + xr.y,
                                    acc[i][jb*4+2] + xr.z, acc[i][jb*4+3] + xr.w);
            *reinterpret_cast<float4*>(y1 + row * D_ + n0 + c0 + jb * 4) = ov;
        }
    }
}

// ---------------------------------------------------------------------------
// y2 = relu(cos(h[:,:8])cos(theta) @ w1^T) @ w2^T + h
// grid (M/128, 768/128), block 256, 8x8 per thread. t never hits HBM.
// ---------------------------------------------------------------------------
__global__ __launch_bounds__(256, 2)
void ffn_kernel(const float* __restrict__ hin, const float* __restrict__ theta,
                const float* __restrict__ w1, const float* __restrict__ w2,
                float* __restrict__ y2)
{
    __shared__ float Ts[128 * 64];
    __shared__ float Bs[128 * 64];
    __shared__ float meas_s[128][9];    // +1 pad: conflict-free scalar reads
    __shared__ float w1s[64][9];        // +1 pad
    const int tid = threadIdx.x;
    const int m0 = blockIdx.x * 128, n0 = blockIdx.y * 128;
    const int rg = tid >> 4, cg = tid & 15;
    const int r0 = rg * 8, c0 = cg * 8;
    const int c0t = cg * 4;             // t-tile col base (4 cols/thread)

    // meas for this block's 128 rows (computed once)
    if (tid < 128) {
        const float* hp = hin + (size_t)(m0 + tid) * D_;
        #pragma unroll
        for (int q = 0; q < NQ_; ++q)
            meas_s[tid][q] = cosf(hp[q]) * cosf(theta[q]);
    }

    float acc[8][8];
    #pragma unroll
    for (int i = 0; i < 8; ++i)
        #pragma unroll
        for (int j = 0; j < 8; ++j) acc[i][j] = 0.f;

    for (int k0 = 0; k0 < FFN_; k0 += 64) {
        __syncthreads();                 // prev main-loop reads done; meas_s visible
        #pragma unroll
        for (int it = 0; it < 8; ++it) {
            int idx = tid + it * 256;
            int r = idx >> 4, cb = idx & 15;
            float4 vb = *reinterpret_cast<const float4*>(w2 + (size_t)(n0 + r) * FFN_ + k0 + cb * 4);
            *reinterpret_cast<float4*>(&Bs[r * 64 + ((cb ^ SWZ(r)) << 2)]) = vb;
        }
        if (tid < 128) {                 // w1 rows k0..k0+63 (512 floats)
            float4 vw = *reinterpret_cast<const float4*>(w1 + (size_t)k0 * NQ_ + tid * 4);
            int row = tid >> 1, q0 = (tid & 1) * 4;
            w1s[row][q0 + 0] = vw.x; w1s[row][q0 + 1] = vw.y;
            w1s[row][q0 + 2] = vw.z; w1s[row][q0 + 3] = vw.w;
        }
        __syncthreads();

        // build t tile: t[r][c] = relu(sum_q meas[r][q] * w1[k0+c][q])
        #pragma unroll
        for (int i = 0; i < 8; ++i) {
            int r = r0 + i;
            #pragma unroll
            for (int j = 0; j < 4; ++j) {
                int c = c0t + j;
                float t = 0.f;
                #pragma unroll
                for (int q = 0; q < NQ_; ++q) t = fmaf(meas_s[r][q], w1s[c][q], t);
                t = fmaxf(t, 0.f);
                Ts[r * 64 + ((((c >> 2) ^ SWZ(r)) << 2) | (c & 3))] = t;
            }
        }
        __syncthreads();

        for (int cb = 0; cb < 16; ++cb) {
            float4 a4[8], b4[8];
            #pragma unroll
            for (int i = 0; i < 8; ++i) {
                int r = r0 + i;
                a4[i] = *reinterpret_cast<const float4*>(&Ts[r * 64 + ((cb ^ SWZ(r)) << 2)]);
            }
            #pragma unroll
            for (int j = 0; j < 8; ++j) {
                int c = c0 + j;
                b4[j] = *reinterpret_cast<const float4*>(&Bs[c * 64 + ((cb ^ SWZ(c)) << 2)]);
            }
            #pragma unroll
            for (int i = 0; i < 8; ++i)
                #pragma unroll
                for (int j = 0; j < 8; ++j) {
                    acc[i][j] = fmaf(a4[i].x, b4[j].x, acc[i][j]);
                    acc[i][j] = fmaf(a4[i].y, b4[j].y, acc[i][j]);
                    acc[i][j] = fmaf(a4[i].z, b4[j].z, acc[i][j]);
                    acc[i][j] = fmaf(a4[i].w, b4[j].w, acc[i][j]);
                }
        }
    }

    #pragma unroll
    for (int i = 0; i < 8; ++i) {
        size_t row = (size_t)m0 + r0 + i;
        #pragma unroll
        for (int jb = 0; jb < 2; ++jb) {
            float4 hr = *reinterpret_cast<const float4*>(hin + row * D_ + n0 + c0 + jb * 4);
            float4 ov = make_float4(acc[i][jb*4+0] + hr.x, acc[i][jb*4+1] + hr.y,
                                    acc[i][jb*4+2] + hr.z, acc[i][jb*4+3] + hr.w);
            *reinterpret_cast<float4*>(y2 + row * D_ + n0 + c0 + jb * 4) = ov;
        }
    }
}

// ---------------------------------------------------------------------------
// out = LayerNorm(in) * g + b.  One wave per row. grid M/4, block 256.
// ---------------------------------------------------------------------------
__global__ __launch_bounds__(256, 4)
void ln_kernel(const float* __restrict__ in, const float* __restrict__ g,
               const float* __restrict__ bt, float* __restrict__ out)
{
    const int wave = threadIdx.x >> 6, lane = threadIdx.x & 63;
    const size_t row = (size_t)blockIdx.x * 4 + wave;
    const float* p = in + row * D_;
    float v[12];
    float sum = 0.f;
    #pragma unroll
    for (int c = 0; c < 3; ++c) {
        float4 f = *reinterpret_cast<const float4*>(p + (c * 64 + lane) * 4);
        v[c*4+0] = f.x; v[c*4+1] = f.y; v[c*4+2] = f.z; v[c*4+3] = f.w;
        sum += (f.x + f.y) + (f.z + f.w);
    }
    #pragma unroll
    for (int msk = 1; msk < 64; msk <<= 1) sum += __shfl_xor(sum, msk);
    const float mu = sum * (1.0f / 768.0f);
    float vs = 0.f;
    #pragma unroll
    for (int k = 0; k < 12; ++k) { float d = v[k] - mu; vs = fmaf(d, d, vs); }
    #pragma unroll
    for (int msk = 1; msk < 64; msk <<= 1) vs += __shfl_xor(vs, msk);
    const float rstd = rsqrtf(vs * (1.0f / 768.0f) + 1e-5f);
    float* po = out + row * D_;
    #pragma unroll
    for (int c = 0; c < 3; ++c) {
        const int base = (c * 64 + lane) * 4;
        float4 gg = *reinterpret_cast<const float4*>(g + base);
        float4 bb2 = *reinterpret_cast<const float4*>(bt + base);
        float4 r;
        r.x = (v[c*4+0] - mu) * rstd * gg.x + bb2.x;
        r.y = (v[c*4+1] - mu) * rstd * gg.y + bb2.y;
        r.z = (v[c*4+2] - mu) * rstd * gg.z + bb2.z;
        r.w = (v[c*4+3] - mu) * rstd * gg.w + bb2.w;
        *reinterpret_cast<float4*>(po + base) = r;
    }
}

// ---------------------------------------------------------------------------
extern "C" void kernel_launch(void* const* d_in, const int* in_sizes, int n_in,
                              void* d_out, int out_size, void* d_ws, size_t ws_size,
                              hipStream_t stream)
{
    const float* x   = (const float*)d_in[0];
    const float* cw  = (const float*)d_in[1];
    const float* th  = (const float*)d_in[2];
    const float* w1  = (const float*)d_in[3];
    const float* w2  = (const float*)d_in[4];
    const float* g1  = (const float*)d_in[5];
    const float* b1  = (const float*)d_in[6];
    const float* g2  = (const float*)d_in[7];
    const float* b2  = (const float*)d_in[8];
    float* out = (float*)d_out;

    const size_t NE = (size_t)M_ * D_;            // 6,291,456 floats (25.2 MB)
    float* ws   = (float*)d_ws;
    float* attn = ws;                             // region A
    float* hbuf = ws + NE;                        // region B
    float* y1   = out;                            // d_out doubles as y1 scratch
    float* y2   = ws;                             // region A reused (attn dead)

    attn_kernel <<<dim3(S_ / 128, H_, B_), 256, 0, stream>>>(x, attn);
    gemm_combine<<<dim3(M_ / 128, D_ / 128), 256, 0, stream>>>(attn, cw, x, y1);
    ln_kernel   <<<dim3(M_ / 4), 256, 0, stream>>>(y1, g1, b1, hbuf);
    ffn_kernel  <<<dim3(M_ / 128, D_ / 128), 256, 0, stream>>>(hbuf, th, w1, w2, y2);
    ln_kernel   <<<dim3(M_ / 4), 256, 0, stream>>>(y2, g2, b2, out);
}

// Round 2
// 543.899 us; speedup vs baseline: 3.1824x; 3.1824x over previous
//
#include <hip/hip_runtime.h>
#include <math.h>

// ---------------------------------------------------------------------------
// TransformerBlockQuantum — bf16 MFMA round
//   attn (flash, bf16 MFMA) -> combine GEMM (bf16 MFMA) -> LN1 ->
//   quantum FFN (bf16 MFMA, T built on the fly) -> LN2
// fp32 kept for: softmax stats, accumulators, residuals, LN, h, meas.
// ---------------------------------------------------------------------------

#define B_    4
#define S_    2048
#define D_    768
#define H_    12
#define DK_   64
#define FFN_  3072
#define NQ_   8
#define M_    (B_ * S_)          // 8192 rows

typedef __attribute__((ext_vector_type(8))) short bf16x8;   // 8 bf16 = 4 VGPR
typedef __attribute__((ext_vector_type(4))) float f32x4;

static __device__ __forceinline__ unsigned short f2bf(float f) {
    unsigned u = __float_as_uint(f);
    unsigned r = (u + 0x7FFFu + ((u >> 16) & 1u)) >> 16;   // RNE
    return (unsigned short)r;
}
static __device__ __forceinline__ unsigned pk2(float a, float b) {
    return (unsigned)f2bf(a) | ((unsigned)f2bf(b) << 16);
}
static __device__ __forceinline__ bf16x8 pack8(float4 a, float4 b) {
    bf16x8 r;
    r[0] = (short)f2bf(a.x); r[1] = (short)f2bf(a.y);
    r[2] = (short)f2bf(a.z); r[3] = (short)f2bf(a.w);
    r[4] = (short)f2bf(b.x); r[5] = (short)f2bf(b.y);
    r[6] = (short)f2bf(b.z); r[7] = (short)f2bf(b.w);
    return r;
}

// ---------------------------------------------------------------------------
// Flash attention, bf16 MFMA. grid (S/128, H, B), block 256 (4 waves).
// Wave w owns q-rows [q0+32w, q0+32w+32). Q hoisted to regs from global.
// K tile (row-major) + Vt tile (transposed) in LDS, XOR chunk-swizzled.
// Output written as bf16 (feeds combine GEMM).
// ---------------------------------------------------------------------------
__global__ __launch_bounds__(256, 2)
void attn_mfma(const float* __restrict__ x, unsigned short* __restrict__ attnb)
{
    __shared__ __align__(16) short Ks[64 * 64];     // [kv][kdim]  8 KB
    __shared__ __align__(16) short Vt[64 * 64];     // [d][kv]     8 KB
    __shared__ __align__(16) short Ps[4 * 32 * 64]; // per-wave P 16 KB

    const int tid = threadIdx.x;
    const int w   = tid >> 6;
    const int l   = tid & 63;
    const int g   = l >> 4;          // 0..3
    const int l15 = l & 15;

    const int q0 = blockIdx.x * 128;
    const int hh = blockIdx.y;
    const int bb = blockIdx.z;

    const float* xh = x + ((size_t)bb * S_) * D_ + hh * DK_;   // head slice base

    // ---- hoist Q fragments: qf[qt][ks], rows q0+32w+qt*16+l15, k=ks*32+g*8 ----
    bf16x8 qf[2][2];
    {
        const float* xq = xh + (size_t)(q0 + w * 32) * D_;
        #pragma unroll
        for (int qt = 0; qt < 2; ++qt)
            #pragma unroll
            for (int ks = 0; ks < 2; ++ks) {
                const float* p = xq + (size_t)(qt * 16 + l15) * D_ + ks * 32 + g * 8;
                float4 f0 = *reinterpret_cast<const float4*>(p);
                float4 f1 = *reinterpret_cast<const float4*>(p + 4);
                qf[qt][ks] = pack8(f0, f1);
            }
    }

    f32x4 oacc[2][4];
    float mrun[2][4], lrun[2][4];
    #pragma unroll
    for (int qt = 0; qt < 2; ++qt)
        #pragma unroll
        for (int i = 0; i < 4; ++i) {
            oacc[qt][i] = (f32x4){0.f, 0.f, 0.f, 0.f};
            mrun[qt][i] = -3.0e38f; lrun[qt][i] = 0.f;
        }

    short* Pw = Ps + w * 32 * 64;

    for (int kt = 0; kt < S_ / 64; ++kt) {
        __syncthreads();                        // prior reads of Ks/Vt done
        const float* xk = xh + (size_t)(kt * 64) * D_;

        // ---- stage K row-major (chunk-swizzled): 512 chunks of 16B ----
        #pragma unroll
        for (int it = 0; it < 2; ++it) {
            int c = tid + it * 256;             // 0..511
            int r = c >> 3, b = c & 7;
            const float* p = xk + (size_t)r * D_ + b * 8;
            float4 f0 = *reinterpret_cast<const float4*>(p);
            float4 f1 = *reinterpret_cast<const float4*>(p + 4);
            *reinterpret_cast<bf16x8*>(&Ks[r * 64 + ((b ^ (r & 7)) << 3)]) = pack8(f0, f1);
        }
        // ---- stage Vt transposed (pairs along kv, u32 writes) ----
        {
            int kv0 = (tid & 31) * 2;
            int dch = tid >> 5;                 // 0..7
            unsigned* Vt32 = reinterpret_cast<unsigned*>(Vt);
            #pragma unroll
            for (int dp = 0; dp < 2; ++dp) {
                int d0 = dp * 32 + dch * 4;
                float4 fa = *reinterpret_cast<const float4*>(xk + (size_t)kv0 * D_ + d0);
                float4 fb = *reinterpret_cast<const float4*>(xk + (size_t)(kv0 + 1) * D_ + d0);
                const float* pa = reinterpret_cast<const float*>(&fa);
                const float* pb = reinterpret_cast<const float*>(&fb);
                #pragma unroll
                for (int j = 0; j < 4; ++j) {
                    int d = d0 + j;
                    Vt32[d * 32 + ((kv0 >> 1) ^ ((d & 7) << 2))] = pk2(pa[j], pb[j]);
                }
            }
        }
        __syncthreads();

        // ---- S = Q K^T ----
        f32x4 sacc[2][4];
        #pragma unroll
        for (int qt = 0; qt < 2; ++qt)
            #pragma unroll
            for (int kj = 0; kj < 4; ++kj) sacc[qt][kj] = (f32x4){0.f, 0.f, 0.f, 0.f};

        #pragma unroll
        for (int ks = 0; ks < 2; ++ks) {
            bf16x8 kf[4];
            #pragma unroll
            for (int kj = 0; kj < 4; ++kj) {
                int r = kj * 16 + l15;
                kf[kj] = *reinterpret_cast<const bf16x8*>(
                    &Ks[r * 64 + (((ks * 4 + g) ^ (r & 7)) << 3)]);
            }
            #pragma unroll
            for (int qt = 0; qt < 2; ++qt)
                #pragma unroll
                for (int kj = 0; kj < 4; ++kj)
                    sacc[qt][kj] = __builtin_amdgcn_mfma_f32_16x16x32_bf16(
                        qf[qt][ks], kf[kj], sacc[qt][kj], 0, 0, 0);
        }

        // ---- online softmax + P -> LDS (bf16) ----
        #pragma unroll
        for (int qt = 0; qt < 2; ++qt) {
            #pragma unroll
            for (int reg = 0; reg < 4; ++reg) {
                float s0 = sacc[qt][0][reg] * 0.125f;
                float s1 = sacc[qt][1][reg] * 0.125f;
                float s2 = sacc[qt][2][reg] * 0.125f;
                float s3 = sacc[qt][3][reg] * 0.125f;
                float mx = fmaxf(fmaxf(s0, s1), fmaxf(s2, s3));
                #pragma unroll
                for (int msk = 1; msk < 16; msk <<= 1) mx = fmaxf(mx, __shfl_xor(mx, msk));
                float mnew = fmaxf(mrun[qt][reg], mx);
                float corr = __expf(mrun[qt][reg] - mnew);
                mrun[qt][reg] = mnew;
                float p0 = __expf(s0 - mnew), p1 = __expf(s1 - mnew);
                float p2 = __expf(s2 - mnew), p3 = __expf(s3 - mnew);
                float ps = (p0 + p1) + (p2 + p3);
                #pragma unroll
                for (int msk = 1; msk < 16; msk <<= 1) ps += __shfl_xor(ps, msk);
                lrun[qt][reg] = lrun[qt][reg] * corr + ps;
                #pragma unroll
                for (int dt = 0; dt < 4; ++dt) oacc[qt][dt][reg] *= corr;
                int q = qt * 16 + g * 4 + reg;
                short* pr = Pw + q * 64;
                int sw = (q & 7) << 3;
                pr[(0 * 16 + l15) ^ sw] = (short)f2bf(p0);
                pr[(1 * 16 + l15) ^ sw] = (short)f2bf(p1);
                pr[(2 * 16 + l15) ^ sw] = (short)f2bf(p2);
                pr[(3 * 16 + l15) ^ sw] = (short)f2bf(p3);
            }
        }

        // ---- O += P V  (A-frags from Ps, B-frags from Vt) ----
        #pragma unroll
        for (int ks = 0; ks < 2; ++ks) {
            bf16x8 pf[2], vf[4];
            #pragma unroll
            for (int qt = 0; qt < 2; ++qt) {
                int q = qt * 16 + l15;
                pf[qt] = *reinterpret_cast<const bf16x8*>(
                    &Pw[q * 64 + (((ks * 4 + g) ^ (q & 7)) << 3)]);
            }
            #pragma unroll
            for (int dt = 0; dt < 4; ++dt) {
                int d = dt * 16 + l15;
                vf[dt] = *reinterpret_cast<const bf16x8*>(
                    &Vt[d * 64 + (((ks * 4 + g) ^ (d & 7)) << 3)]);
            }
            #pragma unroll
            for (int qt = 0; qt < 2; ++qt)
                #pragma unroll
                for (int dt = 0; dt < 4; ++dt)
                    oacc[qt][dt] = __builtin_amdgcn_mfma_f32_16x16x32_bf16(
                        pf[qt], vf[dt], oacc[qt][dt], 0, 0, 0);
        }
    }

    // ---- epilogue: normalize, write bf16 attn[b, q, h*64 + d] ----
    unsigned short* ao = attnb + ((size_t)bb * S_ + q0 + w * 32) * D_ + hh * DK_;
    #pragma unroll
    for (int qt = 0; qt < 2; ++qt)
        #pragma unroll
        for (int reg = 0; reg < 4; ++reg) {
            int q = qt * 16 + g * 4 + reg;
            float inv = 1.0f / lrun[qt][reg];
            unsigned short* rp = ao + (size_t)q * D_;
            #pragma unroll
            for (int dt = 0; dt < 4; ++dt)
                rp[dt * 16 + l15] = f2bf(oacc[qt][dt][reg] * inv);
        }
}

// ---------------------------------------------------------------------------
// y1 = attn(bf16) @ cw^T + x.  grid (M/128, 768/128), block 256 (2x2 waves).
// ---------------------------------------------------------------------------
__global__ __launch_bounds__(256, 2)
void gemm_combine(const unsigned short* __restrict__ A, const float* __restrict__ W,
                  const float* __restrict__ xres, float* __restrict__ y1)
{
    __shared__ __align__(16) short As[128 * 64];   // 16 KB
    __shared__ __align__(16) short Bs[128 * 64];   // 16 KB

    const int tid = threadIdx.x;
    const int w = tid >> 6, l = tid & 63, g = l >> 4, l15 = l & 15;
    const int wr = w >> 1, wc = w & 1;
    const int m0 = blockIdx.x * 128, n0 = blockIdx.y * 128;

    f32x4 acc[4][4];
    #pragma unroll
    for (int i = 0; i < 4; ++i)
        #pragma unroll
        for (int j = 0; j < 4; ++j) acc[i][j] = (f32x4){0.f, 0.f, 0.f, 0.f};

    for (int k0 = 0; k0 < D_; k0 += 64) {
        __syncthreads();
        // A: bf16 source, direct 16B chunk copy
        #pragma unroll
        for (int it = 0; it < 4; ++it) {
            int c = tid + it * 256;             // 0..1023
            int r = c >> 3, b = c & 7;
            bf16x8 v = *reinterpret_cast<const bf16x8*>(
                A + (size_t)(m0 + r) * D_ + k0 + b * 8);
            *reinterpret_cast<bf16x8*>(&As[r * 64 + ((b ^ (r & 7)) << 3)]) = v;
        }
        // B: cw fp32 -> bf16 during staging
        #pragma unroll
        for (int it = 0; it < 4; ++it) {
            int c = tid + it * 256;
            int r = c >> 3, b = c & 7;
            const float* p = W + (size_t)(n0 + r) * D_ + k0 + b * 8;
            float4 f0 = *reinterpret_cast<const float4*>(p);
            float4 f1 = *reinterpret_cast<const float4*>(p + 4);
            *reinterpret_cast<bf16x8*>(&Bs[r * 64 + ((b ^ (r & 7)) << 3)]) = pack8(f0, f1);
        }
        __syncthreads();

        #pragma unroll
        for (int ks = 0; ks < 2; ++ks) {
            bf16x8 af[4], bf[4];
            #pragma unroll
            for (int mt = 0; mt < 4; ++mt) {
                int r = wr * 64 + mt * 16 + l15;
                af[mt] = *reinterpret_cast<const bf16x8*>(
                    &As[r * 64 + (((ks * 4 + g) ^ (r & 7)) << 3)]);
            }
            #pragma unroll
            for (int nt = 0; nt < 4; ++nt) {
                int cc = wc * 64 + nt * 16 + l15;
                bf[nt] = *reinterpret_cast<const bf16x8*>(
                    &Bs[cc * 64 + (((ks * 4 + g) ^ (cc & 7)) << 3)]);
            }
            #pragma unroll
            for (int mt = 0; mt < 4; ++mt)
                #pragma unroll
                for (int nt = 0; nt < 4; ++nt)
                    acc[mt][nt] = __builtin_amdgcn_mfma_f32_16x16x32_bf16(
                        af[mt], bf[nt], acc[mt][nt], 0, 0, 0);
        }
    }

    // epilogue: + residual, fp32 out
    #pragma unroll
    for (int mt = 0; mt < 4; ++mt)
        #pragma unroll
        for (int reg = 0; reg < 4; ++reg) {
            size_t row = (size_t)m0 + wr * 64 + mt * 16 + g * 4 + reg;
            #pragma unroll
            for (int nt = 0; nt < 4; ++nt) {
                int col = n0 + wc * 64 + nt * 16 + l15;
                y1[row * D_ + col] = acc[mt][nt][reg] + xres[row * D_ + col];
            }
        }
}

// ---------------------------------------------------------------------------
// y2 = relu(cos(h[:,:8])cos(theta) @ w1^T) @ w2^T + h
// grid (M/128, 768/128), block 256. T built on the fly (bf16 into LDS).
// ---------------------------------------------------------------------------
__global__ __launch_bounds__(256, 2)
void ffn_mfma(const float* __restrict__ hin, const float* __restrict__ theta,
              const float* __restrict__ w1, const float* __restrict__ w2,
              float* __restrict__ y2)
{
    __shared__ __align__(16) short Ts[128 * 64];   // 16 KB
    __shared__ __align__(16) short Bs[128 * 64];   // 16 KB
    __shared__ float meas_s[128][9];               // 4.6 KB, padded

    const int tid = threadIdx.x;
    const int w = tid >> 6, l = tid & 63, g = l >> 4, l15 = l & 15;
    const int wr = w >> 1, wc = w & 1;
    const int m0 = blockIdx.x * 128, n0 = blockIdx.y * 128;

    if (tid < 128) {
        const float* hp = hin + (size_t)(m0 + tid) * D_;
        #pragma unroll
        for (int q = 0; q < NQ_; ++q)
            meas_s[tid][q] = cosf(hp[q]) * cosf(theta[q]);
    }

    const int cp   = tid & 31;        // u32 col-pair (cols 2cp, 2cp+1)
    const int rblk = tid >> 5;        // 0..7 -> rows rblk*16..+15
    unsigned* Ts32 = reinterpret_cast<unsigned*>(Ts);

    f32x4 acc[4][4];
    #pragma unroll
    for (int i = 0; i < 4; ++i)
        #pragma unroll
        for (int j = 0; j < 4; ++j) acc[i][j] = (f32x4){0.f, 0.f, 0.f, 0.f};

    for (int k0 = 0; k0 < FFN_; k0 += 64) {
        __syncthreads();               // prev MFMA reads done; meas_s visible
        // B: w2 fp32 -> bf16
        #pragma unroll
        for (int it = 0; it < 4; ++it) {
            int c = tid + it * 256;
            int r = c >> 3, b = c & 7;
            const float* p = w2 + (size_t)(n0 + r) * FFN_ + k0 + b * 8;
            float4 f0 = *reinterpret_cast<const float4*>(p);
            float4 f1 = *reinterpret_cast<const float4*>(p + 4);
            *reinterpret_cast<bf16x8*>(&Bs[r * 64 + ((b ^ (r & 7)) << 3)]) = pack8(f0, f1);
        }
        // T tile: t[r][c] = relu(sum_q meas[r][q] * w1[k0+c][q]), bf16 pairs
        {
            const float* wA = w1 + (size_t)(k0 + 2 * cp) * NQ_;
            const float* wB = wA + NQ_;
            float4 a0 = *reinterpret_cast<const float4*>(wA);
            float4 a1 = *reinterpret_cast<const float4*>(wA + 4);
            float4 b0 = *reinterpret_cast<const float4*>(wB);
            float4 b1 = *reinterpret_cast<const float4*>(wB + 4);
            const float* wAa = reinterpret_cast<const float*>(&a0);
            const float* wAb = reinterpret_cast<const float*>(&a1);
            const float* wBa = reinterpret_cast<const float*>(&b0);
            const float* wBb = reinterpret_cast<const float*>(&b1);
            #pragma unroll
            for (int i = 0; i < 16; ++i) {
                int r = rblk * 16 + i;
                float t0 = 0.f, t1 = 0.f;
                #pragma unroll
                for (int q = 0; q < 4; ++q) {
                    float m = meas_s[r][q];
                    t0 = fmaf(m, wAa[q], t0);
                    t1 = fmaf(m, wBa[q], t1);
                }
                #pragma unroll
                for (int q = 0; q < 4; ++q) {
                    float m = meas_s[r][q + 4];
                    t0 = fmaf(m, wAb[q], t0);
                    t1 = fmaf(m, wBb[q], t1);
                }
                t0 = fmaxf(t0, 0.f); t1 = fmaxf(t1, 0.f);
                Ts32[r * 32 + (cp ^ ((r & 7) << 2))] = pk2(t0, t1);
            }
        }
        __syncthreads();

        #pragma unroll
        for (int ks = 0; ks < 2; ++ks) {
            bf16x8 af[4], bf[4];
            #pragma unroll
            for (int mt = 0; mt < 4; ++mt) {
                int r = wr * 64 + mt * 16 + l15;
                af[mt] = *reinterpret_cast<const bf16x8*>(
                    &Ts[r * 64 + (((ks * 4 + g) ^ (r & 7)) << 3)]);
            }
            #pragma unroll
            for (int nt = 0; nt < 4; ++nt) {
                int cc = wc * 64 + nt * 16 + l15;
                bf[nt] = *reinterpret_cast<const bf16x8*>(
                    &Bs[cc * 64 + (((ks * 4 + g) ^ (cc & 7)) << 3)]);
            }
            #pragma unroll
            for (int mt = 0; mt < 4; ++mt)
                #pragma unroll
                for (int nt = 0; nt < 4; ++nt)
                    acc[mt][nt] = __builtin_amdgcn_mfma_f32_16x16x32_bf16(
                        af[mt], bf[nt], acc[mt][nt], 0, 0, 0);
        }
    }

    #pragma unroll
    for (int mt = 0; mt < 4; ++mt)
        #pragma unroll
        for (int reg = 0; reg < 4; ++reg) {
            size_t row = (size_t)m0 + wr * 64 + mt * 16 + g * 4 + reg;
            #pragma unroll
            for (int nt = 0; nt < 4; ++nt) {
                int col = n0 + wc * 64 + nt * 16 + l15;
                y2[row * D_ + col] = acc[mt][nt][reg] + hin[row * D_ + col];
            }
        }
}

// ---------------------------------------------------------------------------
// out = LayerNorm(in) * g + b.  One wave per row. grid M/4, block 256.
// ---------------------------------------------------------------------------
__global__ __launch_bounds__(256, 4)
void ln_kernel(const float* __restrict__ in, const float* __restrict__ g,
               const float* __restrict__ bt, float* __restrict__ out)
{
    const int wave = threadIdx.x >> 6, lane = threadIdx.x & 63;
    const size_t row = (size_t)blockIdx.x * 4 + wave;
    const float* p = in + row * D_;
    float v[12];
    float sum = 0.f;
    #pragma unroll
    for (int c = 0; c < 3; ++c) {
        float4 f = *reinterpret_cast<const float4*>(p + (c * 64 + lane) * 4);
        v[c*4+0] = f.x; v[c*4+1] = f.y; v[c*4+2] = f.z; v[c*4+3] = f.w;
        sum += (f.x + f.y) + (f.z + f.w);
    }
    #pragma unroll
    for (int msk = 1; msk < 64; msk <<= 1) sum += __shfl_xor(sum, msk);
    const float mu = sum * (1.0f / 768.0f);
    float vs = 0.f;
    #pragma unroll
    for (int k = 0; k < 12; ++k) { float d = v[k] - mu; vs = fmaf(d, d, vs); }
    #pragma unroll
    for (int msk = 1; msk < 64; msk <<= 1) vs += __shfl_xor(vs, msk);
    const float rstd = rsqrtf(vs * (1.0f / 768.0f) + 1e-5f);
    float* po = out + row * D_;
    #pragma unroll
    for (int c = 0; c < 3; ++c) {
        const int base = (c * 64 + lane) * 4;
        float4 gg = *reinterpret_cast<const float4*>(g + base);
        float4 bb2 = *reinterpret_cast<const float4*>(bt + base);
        float4 r;
        r.x = (v[c*4+0] - mu) * rstd * gg.x + bb2.x;
        r.y = (v[c*4+1] - mu) * rstd * gg.y + bb2.y;
        r.z = (v[c*4+2] - mu) * rstd * gg.z + bb2.z;
        r.w = (v[c*4+3] - mu) * rstd * gg.w + bb2.w;
        *reinterpret_cast<float4*>(po + base) = r;
    }
}

// ---------------------------------------------------------------------------
extern "C" void kernel_launch(void* const* d_in, const int* in_sizes, int n_in,
                              void* d_out, int out_size, void* d_ws, size_t ws_size,
                              hipStream_t stream)
{
    const float* x   = (const float*)d_in[0];
    const float* cw  = (const float*)d_in[1];
    const float* th  = (const float*)d_in[2];
    const float* w1  = (const float*)d_in[3];
    const float* w2  = (const float*)d_in[4];
    const float* g1  = (const float*)d_in[5];
    const float* b1  = (const float*)d_in[6];
    const float* g2  = (const float*)d_in[7];
    const float* b2  = (const float*)d_in[8];
    float* out = (float*)d_out;

    const size_t NE = (size_t)M_ * D_;           // 6,291,456 elements
    float* ws = (float*)d_ws;
    unsigned short* attnb = (unsigned short*)ws;  // region A (bf16, 12.6 MB)
    float* hbuf = ws + NE;                        // region B (fp32, 25.2 MB)
    float* y1   = out;                            // d_out doubles as y1 scratch
    float* y2   = ws;                             // region A reused (attnb dead)

    attn_mfma   <<<dim3(S_ / 128, H_, B_), 256, 0, stream>>>(x, attnb);
    gemm_combine<<<dim3(M_ / 128, D_ / 128), 256, 0, stream>>>(attnb, cw, x, y1);
    ln_kernel   <<<dim3(M_ / 4), 256, 0, stream>>>(y1, g1, b1, hbuf);
    ffn_mfma    <<<dim3(M_ / 128, D_ / 128), 256, 0, stream>>>(hbuf, th, w1, w2, y2);
    ln_kernel   <<<dim3(M_ / 4), 256, 0, stream>>>(y2, g2, b2, out);
}